// Round 21
// baseline (79.838 us; speedup 1.0000x reference)
//
#include <hip/hip_runtime.h>
#include <hip/hip_bf16.h>
#include <math.h>

// Decoder: h = relu(cat @ W_h + b_h); t = selu(h @ W1 + b1);
// x = sigmoid(t @ W2 + b2); loss = sum_w(softplus(z) - z*img)   [== -(BCE log-lik)]
// R = S*B = 4096 rows; Hn=512, bott=160, P=12288 = 192 groups * 64 (w).

#define SELU_SCALE 1.0507009873554804934193349852946f
#define SELU_ALPHA 1.6732632423543772848170429916717f

typedef __attribute__((ext_vector_type(8))) short bf16x8;   // 8 bf16 (4 VGPRs)
typedef __attribute__((ext_vector_type(4))) float f32x4;    // MFMA accumulator

static __device__ __forceinline__ short f2bf(float x) {
    __hip_bfloat16 h = __float2bfloat16(x);
    short s;
    __builtin_memcpy(&s, &h, 2);
    return s;
}

// ---------------- P: merged producer (dec_fused ∥ w2_pack) -----------------
// (R18-verified, unchanged)
__global__ __launch_bounds__(512) void producer_kernel(
    const float* __restrict__ digits,   // [R,10]
    const float* __restrict__ styles,   // [R,50]
    const float* __restrict__ Wh,       // [60,512]
    const float* __restrict__ bh,       // [512]
    const float* __restrict__ W1,       // [512,160]
    const float* __restrict__ b1,       // [160]
    const float* __restrict__ W2,       // [160,12288]
    __hip_bfloat16* __restrict__ w2f,   // [3840 chunks][512 shorts]
    __hip_bfloat16* __restrict__ tf)    // [1280 chunks][512 shorts]
{
    __shared__ __align__(16) char smem[46912];
    const int tid = threadIdx.x;

    if (blockIdx.x < 256) {
        float (*cat_s)[60] = (float(*)[60])smem;
        float* h_s = (float*)(smem + 3840);
        float (*t_s)[161] = (float(*)[161])(smem + 3840 + 32768);
        const int rowBase = blockIdx.x * 16;

        for (int i = tid; i < 16 * 60; i += 512) {
            const int r = i / 60, k = i % 60;
            const int row = rowBase + r;
            cat_s[r][k] = (k < 10) ? digits[row * 10 + k]
                                   : styles[row * 50 + (k - 10)];
        }
        __syncthreads();

        {
            float acc[16];
            const float bias = bh[tid];
#pragma unroll
            for (int r = 0; r < 16; ++r) acc[r] = bias;
            for (int k = 0; k < 60; ++k) {
                const float w = Wh[k * 512 + tid];
#pragma unroll
                for (int r = 0; r < 16; ++r) acc[r] = fmaf(cat_s[r][k], w, acc[r]);
            }
#pragma unroll
            for (int r = 0; r < 16; ++r)
                h_s[r * 512 + tid] = fmaxf(acc[r], 0.0f);
        }
        __syncthreads();

        if (tid < 320) {
            const int rh = (tid >= 160) ? 1 : 0;
            const int col = tid - rh * 160;
            const int r0 = rh * 8;
            float acc[8];
            const float bias = b1[col];
#pragma unroll
            for (int r = 0; r < 8; ++r) acc[r] = bias;

#pragma unroll 4
            for (int k = 0; k < 512; k += 4) {
                const float w0 = W1[(size_t)(k + 0) * 160 + col];
                const float w1 = W1[(size_t)(k + 1) * 160 + col];
                const float w2 = W1[(size_t)(k + 2) * 160 + col];
                const float w3 = W1[(size_t)(k + 3) * 160 + col];
#pragma unroll
                for (int r = 0; r < 8; ++r) {
                    const float4 hv = *(const float4*)&h_s[(r0 + r) * 512 + k];
                    float a = acc[r];
                    a = fmaf(hv.x, w0, a);
                    a = fmaf(hv.y, w1, a);
                    a = fmaf(hv.z, w2, a);
                    a = fmaf(hv.w, w3, a);
                    acc[r] = a;
                }
            }
#pragma unroll
            for (int r = 0; r < 8; ++r) {
                const float z = acc[r];
                const float s = (z > 0.0f) ? (SELU_SCALE * z)
                                           : (SELU_SCALE * SELU_ALPHA * expm1f(z));
                t_s[r0 + r][col] = s;
            }
        }
        __syncthreads();

        if (tid < 320) {
            const int kk = tid >> 6;
            const int l = tid & 63;
            const int lr = l & 15, lh = l >> 4;
            bf16x8 v;
#pragma unroll
            for (int j = 0; j < 8; ++j)
                v[j] = f2bf(t_s[lr][kk * 32 + lh * 8 + j]);
            *(bf16x8*)((short*)tf + ((size_t)blockIdx.x * 5 + kk) * 512 + l * 8) = v;
        }
    } else {
        float (*tile)[64] = (float(*)[64])(smem + (tid >> 8) * 8192);
        const int p = (blockIdx.x - 256) * 2 + (tid >> 8);   // 0..959
        const int t256 = tid & 255;
        const int bx = p / 5, by = p % 5;
        const int colBase = bx * 64;
        const int kBase = by * 32;

        for (int i = t256; i < 32 * 64; i += 256)
            tile[i >> 6][i & 63] =
                W2[(size_t)(kBase + (i >> 6)) * 12288 + colBase + (i & 63)];
        __syncthreads();

        const int c16 = t256 >> 6;
        const int lane = t256 & 63;
        const int lr = lane & 15, lh = lane >> 4;

        bf16x8 v;
#pragma unroll
        for (int j = 0; j < 8; ++j)
            v[j] = f2bf(tile[lh * 8 + j][c16 * 16 + lr]);

        const size_t chunk = (size_t)(bx * 4 + c16) * 5 + by;
        *(bf16x8*)((short*)w2f + chunk * 512 + lane * 8) = v;
    }
}

// ---------------- K3: all-register GEMM, rolling pipeline, no barrier ------
// 1-D grid 1536, XCD decode as R20 (colBlk pinned to XCD; w2f HBM ~once/col).
// Block = 4 fully-independent waves; col group FIXED; 8 row-tiles of 64 rows.
// CHANGE vs R20: aW (the block's 20 w2 fragment chunks, col-invariant across
// all 8 tiles) lives in REGISTERS (80 VGPR), loaded ONCE per wave from
// global (L2/XCD-hot, amortized 8x -- not R15's per-tile reload). This
// deletes w2s LDS (20 KB), ~1 GB of aggregate ds_read_b128 traffic, and the
// only block barrier. GEMM is now pure-register MFMA. launch_bounds(256,2):
// ~195 VGPR, 8 waves/CU.
//  - ims: per-wave 2 x 4 KB slabs, DMA'd one tile ahead (R6 swizzle).
//  - bT: 2 register banks, loaded one tile ahead.
//  - ONE counted s_waitcnt vmcnt(9) per iteration, AFTER the GEMM (T4).
//    In-order accounting: compiler's own bT-register wait retires
//    everything older (incl. ims_it's predecessors); vmcnt(9) then retires
//    ims_it leaving bT_{it+1}(5)+ims_{it+1}(4)=9 in flight. Last iter: 0.
//  - loop body has ZERO stores (parts in regs; stored after the loop).
__global__ __launch_bounds__(256, 2) void out_loss_mfma_kernel(
    const __hip_bfloat16* __restrict__ tf,   // fragment-packed t
    const __hip_bfloat16* __restrict__ w2f,  // fragment-packed W2
    const float* __restrict__ b2,            // [12288]
    const float* __restrict__ images,        // [4096,12288]
    float* __restrict__ out)                 // [4096,192]
{
    __shared__ float ims[4][2][1024];        // 32 KB: per-wave 2 slabs 16x64

    const int tid = threadIdx.x;
    const int lane = tid & 63;
    const int wv = tid >> 6;
    const int bid = blockIdx.x;              // 0..1535
    const int colBlk = (bid & 7) * 24 + ((bid >> 3) % 24);   // 0..191
    const int rowGen = bid / 192;            // 0..7
    const int colBase = colBlk * 64;
    const int lr = lane & 15;
    const int lh = lane >> 4;

    const short* wfb = (const short*)w2f;
    const short* tfb = (const short*)tf;
    const char* imb = (const char*)images;

    const int rsub = lane >> 4;               // DMA: row within instr
    const int m16 = lane & 15;                // DMA: 16B chunk in 256B row

    // wave's row base for tile it: rowGen*512 + it*64 + wv*16
    const int rowW = rowGen * 512 + wv * 16;

#define ISSUE_IMS(it_, slot_)                                                  \
    {                                                                          \
        const int rb = rowW + (it_) * 64;                                      \
        _Pragma("unroll")                                                      \
        for (int w = 0; w < 4; ++w) {                                          \
            const int r = w * 4 + rsub;                                        \
            const size_t gb = (size_t)(rb + r) * 49152 + (size_t)colBase * 4   \
                            + (size_t)((16 * m16) ^ ((r & 15) << 4));          \
            __builtin_amdgcn_global_load_lds((const uint32_t*)(imb + gb),      \
                (uint32_t*)&ims[wv][slot_][w * 256], 16, 0, 0);                \
        }                                                                      \
    }

#define ISSUE_BT(it_, bank_)                                                   \
    {                                                                          \
        const int r16 = (rowW + (it_) * 64) >> 4;                              \
        _Pragma("unroll")                                                      \
        for (int kk = 0; kk < 5; ++kk)                                         \
            bT[bank_][kk] = *(const bf16x8*)(tfb                               \
                + ((size_t)r16 * 5 + kk) * 512 + lane * 8);                    \
    }

    bf16x8 bT[2][5];
    bf16x8 aW[20];                            // col-invariant: loaded once

    // ---- prologue: bc, aW(20), bT0, ims0 | bT1, ims1 ----
    float4 bc[4];
#pragma unroll
    for (int c = 0; c < 4; ++c)
        bc[c] = *(const float4*)(b2 + colBase + c * 16 + lh * 4);
    {
        const size_t chunkBase = (size_t)colBlk * 20;
#pragma unroll
        for (int ch = 0; ch < 20; ++ch)
            aW[ch] = *(const bf16x8*)(wfb + (chunkBase + ch) * 512 + lane * 8);
    }
    ISSUE_BT(0, 0)
    ISSUE_IMS(0, 0)
    ISSUE_BT(1, 1)
    ISSUE_IMS(1, 1)

    float parts[8];

#pragma unroll
    for (int it = 0; it < 8; ++it) {
        // ---- GEMM: pure-register MFMA (aW x bT[it&1]) ----
        // (compiler's bT-register wait retires all vmem older than ims_it)
        f32x4 acc[4] = {};
#pragma unroll
        for (int kk = 0; kk < 5; ++kk)
#pragma unroll
            for (int c = 0; c < 4; ++c)
                acc[c] = __builtin_amdgcn_mfma_f32_16x16x32_bf16(
                    aW[c * 5 + kk], bT[it & 1][kk], acc[c], 0, 0, 0);

        // ---- counted fence AFTER the GEMM: retire ims_it only ----
        if (it < 7) {
            asm volatile("s_waitcnt vmcnt(9)" ::: "memory");
        } else {
            asm volatile("s_waitcnt vmcnt(0)" ::: "memory");
        }
        __builtin_amdgcn_sched_barrier(0);

        // ---- slab -> regs, then fence before slab reuse ----
        float4 img[4];
#pragma unroll
        for (int c = 0; c < 4; ++c) {
            const int fidx = lr * 64 + ((lh * 4 + c * 16) ^ (lr << 2));
            img[c] = *(const float4*)&ims[wv][it & 1][fidx];  // ds_read_b128
        }
        asm volatile("s_waitcnt lgkmcnt(0)" ::: "memory");
        __builtin_amdgcn_sched_barrier(0);

        // ---- prefetch tile it+2 into the bank/slab just freed ----
        if (it < 6) {
            ISSUE_BT(it + 2, it & 1)
            ISSUE_IMS(it + 2, it & 1)
        }

        // ---- epilogue math (no stores) ----
        float mx = 0.f;   // Σ max(z,0)
        float pr = 1.f;   // Π (1+e^{-|z|})  (16 terms, fp32-safe)
        float zi = 0.f;   // Σ z*im
#pragma unroll
        for (int c = 0; c < 4; ++c) {
            const float imv[4] = {img[c].x, img[c].y, img[c].z, img[c].w};
            const float bcv[4] = {bc[c].x, bc[c].y, bc[c].z, bc[c].w};
#pragma unroll
            for (int j = 0; j < 4; ++j) {
                const float z = acc[c][j] + bcv[j];
                mx += fmaxf(z, 0.0f);
                pr *= 1.0f + __expf(-fabsf(z));   // native v_exp_f32
                zi = fmaf(z, imv[j], zi);
            }
        }
        float part = mx + __logf(pr) - zi;        // native v_log_f32
        part += __shfl_xor(part, 16);
        part += __shfl_xor(part, 32);

        parts[it] = part;                         // it is compile-time const
    }

    // ---- stores (outside the counted-vmcnt loop) ----
    if (lane < 16) {
#pragma unroll
        for (int it = 0; it < 8; ++it)
            out[(size_t)(rowW + it * 64 + lane) * 192 + colBlk] = parts[it];
    }
#undef ISSUE_IMS
#undef ISSUE_BT
}

extern "C" void kernel_launch(void* const* d_in, const int* in_sizes, int n_in,
                              void* d_out, int out_size, void* d_ws, size_t ws_size,
                              hipStream_t stream) {
    const float* digits = (const float*)d_in[0];  // [8,512,10]
    const float* styles = (const float*)d_in[1];  // [8,512,50]
    const float* images = (const float*)d_in[2];  // [8,512,3,64,64]
    const float* Wh     = (const float*)d_in[3];  // [60,512]
    const float* bh     = (const float*)d_in[4];  // [512]
    const float* W1     = (const float*)d_in[5];  // [512,160]
    const float* b1     = (const float*)d_in[6];  // [160]
    const float* W2     = (const float*)d_in[7];  // [160,12288]
    const float* b2     = (const float*)d_in[8];  // [12288]
    float* out = (float*)d_out;                   // [4096,192]

    // workspace (~5.3 MB): w2f bf16 [3840*512] | tf bf16 [1280*512]
    __hip_bfloat16* w2f = (__hip_bfloat16*)d_ws;
    __hip_bfloat16* tf  = w2f + (size_t)12288 * 160;

    producer_kernel<<<736, 512, 0, stream>>>(digits, styles, Wh, bh, W1, b1,
                                             W2, w2f, tf);

    out_loss_mfma_kernel<<<1536, 256, 0, stream>>>(tf, w2f, b2, images, out);
}